// Round 4
// baseline (123.779 us; speedup 1.0000x reference)
//
#include <hip/hip_runtime.h>

#define BSZ 8
#define PN  2048
#define CIN 512
#define CAP 2048
#define NG  64            // slices (global load balance)
#define KMAX 768          // max slice elems: ceil(24*2048/64) rounded to 8

// ws layout (bytes):
//   accum @ 0        : 8 floats (S[4], imb[4])
//   cnt   @ 32       : 1 int (k_back completion counter)
//   meta  @ 64       : 24 ints (padded list length per (b,c))
//   sList @ 1024     : 24*2048 floats (score, list order)
//   areaL @ 197632   : 24*2048 floats (area, list order)
//   roiL  @ 394240   : 24*2048 float4 (roi, list order)
//   pbn   @ 1180672  : 24*NG*2048 floats (partial best numerator)
//   pbd   @ 13763584 : 24*NG*2048 floats (partial best denominator)
//   pbp   @ 26346496 : 24*NG*2048 ints   (partial best list pos)
// total ~39 MB (ws is 256 MiB per harness poison fill)

// ---------------- K1: fc+softmax (blocks 0..1023) | select (1024..1047) -----
__global__ __launch_bounds__(256) void k_front(
    const float* __restrict__ inp, const float* __restrict__ fcw,
    const float* __restrict__ fcb, const float* __restrict__ ps,
    const float* __restrict__ labels, const float* __restrict__ rois,
    float* __restrict__ logit, float* __restrict__ accum, int* __restrict__ cnt0,
    int* __restrict__ meta, float* __restrict__ sList,
    float* __restrict__ areaL, float4* __restrict__ roiList)
{
  const int t = threadIdx.x;
  if (blockIdx.x < 1024) {
    const int gw   = (blockIdx.x * 256 + t) >> 6;   // 0..4095
    const int lane = t & 63;
    const int kb   = lane << 2;
    const float4 wa0 = *(const float4*)(fcw + (kb + 0) * 4);
    const float4 wa1 = *(const float4*)(fcw + (kb + 1) * 4);
    const float4 wa2 = *(const float4*)(fcw + (kb + 2) * 4);
    const float4 wa3 = *(const float4*)(fcw + (kb + 3) * 4);
    const float4 wb0 = *(const float4*)(fcw + (256 + kb + 0) * 4);
    const float4 wb1 = *(const float4*)(fcw + (256 + kb + 1) * 4);
    const float4 wb2 = *(const float4*)(fcw + (256 + kb + 2) * 4);
    const float4 wb3 = *(const float4*)(fcw + (256 + kb + 3) * 4);
    const float4 bias = *(const float4*)fcb;
    #pragma unroll
    for (int rr = 0; rr < 4; ++rr) {
      const int r = (gw << 2) + rr;                 // row 0..16383
      const float* row = inp + r * CIN;
      const float4 xa = *(const float4*)(row + kb);
      const float4 xb = *(const float4*)(row + 256 + kb);
      float a0 = xa.x*wa0.x + xa.y*wa1.x + xa.z*wa2.x + xa.w*wa3.x
               + xb.x*wb0.x + xb.y*wb1.x + xb.z*wb2.x + xb.w*wb3.x;
      float a1 = xa.x*wa0.y + xa.y*wa1.y + xa.z*wa2.y + xa.w*wa3.y
               + xb.x*wb0.y + xb.y*wb1.y + xb.z*wb2.y + xb.w*wb3.y;
      float a2 = xa.x*wa0.z + xa.y*wa1.z + xa.z*wa2.z + xa.w*wa3.z
               + xb.x*wb0.z + xb.y*wb1.z + xb.z*wb2.z + xb.w*wb3.z;
      float a3 = xa.x*wa0.w + xa.y*wa1.w + xa.z*wa2.w + xa.w*wa3.w
               + xb.x*wb0.w + xb.y*wb1.w + xb.z*wb2.w + xb.w*wb3.w;
      #pragma unroll
      for (int off = 32; off; off >>= 1) {
        a0 += __shfl_xor(a0, off); a1 += __shfl_xor(a1, off);
        a2 += __shfl_xor(a2, off); a3 += __shfl_xor(a3, off);
      }
      if (lane == 0) {
        a0 += bias.x; a1 += bias.y; a2 += bias.z; a3 += bias.w;
        const float m  = fmaxf(fmaxf(a0, a1), fmaxf(a2, a3));
        const float e0 = expf(a0 - m), e1 = expf(a1 - m);
        const float e2 = expf(a2 - m), e3 = expf(a3 - m);
        const float inv = 1.0f / (e0 + e1 + e2 + e3);
        float4 o; o.x = e0*inv; o.y = e1*inv; o.z = e2*inv; o.w = e3*inv;
        *(float4*)(logit + r * 4) = o;
      }
    }
    return;
  }

  // ---- selection -> compacted per-(b,c) lists ----
  const int bc = blockIdx.x - 1024;                 // 0..23
  if (bc == 0) {
    if (t < 8) accum[t] = 0.0f;
    if (t == 8) *cnt0 = 0;
  }
  const int b = bc / 3;
  const int c = bc % 3;
  const int j0 = t * 8;

  float sv[8];
  int   flg = 0, cnt = 0;
  float vmax = -1e30f;
  int   jmax = 0;
  #pragma unroll
  for (int m = 0; m < 8; ++m) {
    const float s = ps[(b * PN + j0 + m) * 4 + c];
    sv[m] = s;
    if (s > 0.5f) { flg |= 1 << m; ++cnt; }
    if (s > vmax) { vmax = s; jmax = j0 + m; }      // ascending: > = first
  }

  __shared__ float lv[256];
  __shared__ int   lj[256];
  __shared__ int   pre[256];
  lv[t] = vmax; lj[t] = jmax; pre[t] = cnt;
  __syncthreads();
  for (int off = 128; off > 0; off >>= 1) {         // argmax reduce
    if (t < off) {
      const float v2 = lv[t + off]; const int j2 = lj[t + off];
      if (v2 > lv[t] || (v2 == lv[t] && j2 < lj[t])) { lv[t] = v2; lj[t] = j2; }
    }
    __syncthreads();
  }
  for (int off = 1; off < 256; off <<= 1) {         // inclusive scan
    const int add = (t >= off) ? pre[t - off] : 0;
    __syncthreads();
    pre[t] += add;
    __syncthreads();
  }
  const int  totalTh = pre[255];
  const int  excl    = pre[t] - cnt;
  const int  jArg    = lj[0];
  const bool lab     = labels[b * 4 + c] != 0.0f;
  const int  L    = (!lab) ? 0 : ((totalTh > 1) ? totalTh : 1);
  const int  Lpad = (L + 7) & ~7;

  __shared__ float4 lastRoi;
  __shared__ float  lastS, lastA;
  float4* dstR = roiList + bc * CAP;
  float*  dstS = sList   + bc * CAP;
  float*  dstA = areaL   + bc * CAP;
  const float4* rb = ((const float4*)rois) + b * PN;

  if (lab) {
    if (totalTh > 1) {
      int pos = excl;
      #pragma unroll
      for (int m = 0; m < 8; ++m) {
        if (flg & (1 << m)) {
          const float4 r = rb[j0 + m];
          const float  a = (r.z - r.x) * (r.w - r.y);
          dstR[pos] = r; dstS[pos] = sv[m]; dstA[pos] = a;
          if (pos == L - 1) { lastRoi = r; lastS = sv[m]; lastA = a; }
          ++pos;
        }
      }
    } else if (t == (jArg >> 3)) {
      const float4 r = rb[jArg];
      const float  a = (r.z - r.x) * (r.w - r.y);
      dstR[0] = r; dstS[0] = sv[jArg & 7]; dstA[0] = a;
      lastRoi = r; lastS = sv[jArg & 7]; lastA = a;
    }
  }
  __syncthreads();
  if (t < Lpad - L) { dstR[L + t] = lastRoi; dstS[L + t] = lastS; dstA[L + t] = lastA; }
  if (t == 0) meta[bc] = Lpad;
}

// ---------------- K2: globally balanced IoU rational-argmax ------------------
// block = (slice g of the 24-list concatenation, 64-i tile). Every block does
// exactly K elems -> perfect load balance; 2048 blocks = 8/CU, one pass.
__global__ __launch_bounds__(256, 8) void k_assign(
    const float* __restrict__ rois, const int* __restrict__ meta,
    const float4* __restrict__ roiL, const float* __restrict__ areaL,
    float* __restrict__ pbn, float* __restrict__ pbd, int* __restrict__ pbp)
{
  const int g     = blockIdx.x >> 5;
  const int itile = blockIdx.x & 31;
  const int t     = threadIdx.x;
  const int lane  = t & 63;
  const int wv    = t >> 6;

  int P[25];                          // uniform -> SGPRs
  P[0] = 0;
  #pragma unroll
  for (int k = 0; k < 24; ++k) P[k + 1] = P[k] + meta[k];
  const int T = P[24];
  const int K = (((T + NG - 1) / NG) + 7) & ~7;
  const int s0 = g * K;
  const int s1 = min(s0 + K, T);
  if (s0 >= s1) return;

  __shared__ float4 sroi[KMAX];
  __shared__ float  sarea[KMAX];
  __shared__ int    spos[KMAX];
  __shared__ float  mrgN[4][64], mrgD[4][64];
  __shared__ int    mrgP[4][64];

  for (int idx = s0 + t; idx < s1; idx += 256) {
    int bcs = 0;
    while (idx >= P[bcs + 1]) ++bcs;  // P uniform, <=24 cmps
    const int local = idx - P[bcs];
    sroi [idx - s0] = roiL [bcs * CAP + local];
    sarea[idx - s0] = areaL[bcs * CAP + local];
    spos [idx - s0] = local;
  }
  __syncthreads();

  auto upd = [](float& n, float& d, int& p, const float4 ri, const float areai,
                const float4 rj, const float aj, const int pos) {
    const float lx = fmaxf(ri.x, rj.x), ly = fmaxf(ri.y, rj.y);
    const float rx = fminf(ri.z, rj.z), ry = fminf(ri.w, rj.w);
    const float ww = fmaxf(rx - lx, 0.0f), hh = fmaxf(ry - ly, 0.0f);
    const float inter = ww * hh;
    const float uni   = areai + aj - inter;         // >= 1 always
    if (inter * d > n * uni) { n = inter; d = uni; p = pos; }
  };

  int idx = s0;
  int bc = 0;
  while (idx >= P[bc + 1]) ++bc;
  int curB = -1;
  float4 ri = make_float4(0.f, 0.f, 0.f, 0.f);
  float areai = 0.f;

  while (idx < s1) {                                // segment loop (uniform)
    const int e = min(s1, P[bc + 1]);
    const int b = bc / 3;
    if (b != curB) {
      ri = ((const float4*)rois)[b * PN + (itile << 6) + lane];
      areai = (ri.z - ri.x) * (ri.w - ri.y);
      curB = b;
    }
    const int len = e - idx;                        // mult of 8
    const int C   = ((len + 31) >> 5) << 3;         // ceil(len/4) to mult 8
    const int o0  = (idx - s0) + wv * C;
    int o1 = o0 + C;
    const int oe = e - s0;
    if (o1 > oe) o1 = oe;

    float nA = -2.0f, dA = 1.0f, nB = -2.0f, dB = 1.0f;
    int   pA = 0, pB = 0;
    for (int o = o0; o < o1; o += 4) {              // dual chains, 4-prefetch
      const float4 r0 = sroi[o],  r1 = sroi[o+1], r2 = sroi[o+2], r3 = sroi[o+3];
      const float  a0 = sarea[o], a1 = sarea[o+1], a2 = sarea[o+2], a3 = sarea[o+3];
      const int    q0 = spos[o],  q1 = spos[o+1],  q2 = spos[o+2],  q3 = spos[o+3];
      upd(nA, dA, pA, ri, areai, r0, a0, q0);
      upd(nB, dB, pB, ri, areai, r2, a2, q2);
      upd(nA, dA, pA, ri, areai, r1, a1, q1);
      upd(nB, dB, pB, ri, areai, r3, a3, q3);
    }
    { const float xB = nB * dA, xA = nA * dB;       // tie -> lower pos
      if (xB > xA || (xB == xA && pB < pA)) { nA = nB; dA = dB; pA = pB; } }

    __syncthreads();                                // mrg reuse guard
    mrgN[wv][lane] = nA; mrgD[wv][lane] = dA; mrgP[wv][lane] = pA;
    __syncthreads();
    if (wv == 0) {
      float n = mrgN[0][lane], d = mrgD[0][lane]; int p = mrgP[0][lane];
      #pragma unroll
      for (int w = 1; w < 4; ++w) {
        const float n2 = mrgN[w][lane], d2 = mrgD[w][lane];
        const int   p2 = mrgP[w][lane];
        const float x2 = n2 * d, x1 = n * d2;
        if (x2 > x1 || (x2 == x1 && p2 < p)) { n = n2; d = d2; p = p2; }
      }
      const int o = (bc * NG + g) * PN + (itile << 6) + lane;
      pbn[o] = n; pbd[o] = d; pbp[o] = p;
    }
    idx = e; ++bc;
  }
}

// ---------------- K3: slice merge + epilogue + loss (fused finalize) ---------
__global__ __launch_bounds__(256) void k_back(
    const float* __restrict__ pbn, const float* __restrict__ pbd,
    const int* __restrict__ pbp, const int* __restrict__ meta,
    const float* __restrict__ sList, const float* __restrict__ logit,
    const float* __restrict__ labels, float* __restrict__ accum,
    int* __restrict__ cnt0, float* __restrict__ loss)
{
  const int t  = threadIdx.x;
  const int gi = blockIdx.x * 256 + t;              // 0..16383
  const int b  = gi >> 11;
  const int i  = gi & (PN - 1);

  int P[25];
  P[0] = 0;
  #pragma unroll
  for (int k = 0; k < 24; ++k) P[k + 1] = P[k] + meta[k];
  const int T = P[24];
  const int K = (((T + NG - 1) / NG) + 7) & ~7;

  float v[3], sc[3];
  #pragma unroll
  for (int c = 0; c < 3; ++c) {
    const int bc = b * 3 + c;
    const int Pb0 = P[bc], Pb1 = P[bc + 1];
    float n = -2.0f, d = 1.0f; int p = 0;
    if (Pb1 > Pb0) {
      const int gs = Pb0 / K;
      const int ge = (Pb1 + K - 1) / K;
      for (int g = gs; g < ge; ++g) {               // g ascending
        const int o = (bc * NG + g) * PN + i;
        const float n2 = pbn[o], d2 = pbd[o];
        const int   p2 = pbp[o];
        const float x2 = n2 * d, x1 = n * d2;
        if (x2 > x1 || (x2 == x1 && p2 < p)) { n = n2; d = d2; p = p2; }
      }
      v[c]  = n / d;                                // exact IEEE divide
      sc[c] = sList[bc * CAP + p];
    } else {
      v[c] = -2.0f; sc[c] = 1.0f;                   // empty list: never wins
    }
  }
  float runI = -1.0f, runw = 1.0f;
  if (v[0] > runI) { runw = sc[0]; runI = v[0]; }
  if (v[1] > runI) { runw = sc[1]; runI = v[1]; }
  if (v[2] > runI) { runw = sc[2]; runI = v[2]; }
  const float y0 = (v[0] > 0.5f) ? 1.0f : 0.0f;
  const float y1 = (v[1] > 0.5f) ? 1.0f : 0.0f;
  const float y2 = (v[2] > 0.5f) ? 1.0f : 0.0f;
  const float y3 = (y0 + y1 + y2 == 0.0f) ? 1.0f : 0.0f;

  const float4 lg = ((const float4*)logit)[gi];
  const float lb0 = labels[b * 4 + 0];
  const float lb1 = labels[b * 4 + 1];
  const float lb2 = labels[b * 4 + 2];

  auto term = [&](const float l, const float yv, const float labv) -> float {
    const float p2 = fminf(fmaxf(l, 1e-7f), 1.0f - 1e-7f);
    const float om = 1.0f - p2;
    const float fl = -yv * logf(p2) * om * om;      // focal, gamma=2
    const float wl = 10.0f * expf(l) * (1.0f - labv) + labv;
    return runw * fl * wl;                          // /imb deferred
  };
  float s[8];
  s[0] = term(lg.x, y0, lb0); s[1] = term(lg.y, y1, lb1);
  s[2] = term(lg.z, y2, lb2); s[3] = term(lg.w, y3, 1.0f);
  s[4] = y0; s[5] = y1; s[6] = y2; s[7] = y3;

  #pragma unroll
  for (int k = 0; k < 8; ++k)
    #pragma unroll
    for (int off = 32; off; off >>= 1) s[k] += __shfl_xor(s[k], off);

  __shared__ float red[4][8];
  const int wv = t >> 6;
  if ((t & 63) == 0)
    #pragma unroll
    for (int k = 0; k < 8; ++k) red[wv][k] = s[k];
  __syncthreads();
  if (t < 8) {
    const float sum = red[0][t] + red[1][t] + red[2][t] + red[3][t];
    atomicAdd(&accum[t], sum);
  }
  __syncthreads();                                  // all atomics issued
  if (t == 0) {
    __threadfence();
    if (atomicAdd(cnt0, 1) == 63) {                 // last block finalizes
      float a[8];
      #pragma unroll
      for (int k = 0; k < 8; ++k) a[k] = atomicAdd(&accum[k], 0.0f);
      float L = 0.0f;
      #pragma unroll
      for (int c = 0; c < 4; ++c) L += a[c] / (a[4 + c] + 1e-7f);
      loss[0] = L * 0.125f;                         // / bs, exact
    }
  }
}

extern "C" void kernel_launch(void* const* d_in, const int* in_sizes, int n_in,
                              void* d_out, int out_size, void* d_ws, size_t ws_size,
                              hipStream_t stream)
{
  (void)in_sizes; (void)n_in; (void)out_size; (void)ws_size;
  const float* inp    = (const float*)d_in[0];
  const float* fcw    = (const float*)d_in[1];
  const float* fcb    = (const float*)d_in[2];
  const float* ps     = (const float*)d_in[3];
  const float* labels = (const float*)d_in[4];
  const float* rois   = (const float*)d_in[5];
  float* out = (float*)d_out;                       // 65536 logit + 1 loss

  char* ws = (char*)d_ws;
  float*  accum = (float*) (ws);
  int*    cnt0  = (int*)   (ws + 32);
  int*    meta  = (int*)   (ws + 64);
  float*  sList = (float*) (ws + 1024);
  float*  areaL = (float*) (ws + 197632);
  float4* roiL  = (float4*)(ws + 394240);
  float*  pbn   = (float*) (ws + 1180672);
  float*  pbd   = (float*) (ws + 13763584);
  int*    pbp   = (int*)   (ws + 26346496);

  k_front <<<1048, 256, 0, stream>>>(inp, fcw, fcb, ps, labels, rois,
                                     out, accum, cnt0, meta, sList, areaL, roiL);
  k_assign<<<NG * 32, 256, 0, stream>>>(rois, meta, roiL, areaL, pbn, pbd, pbp);
  k_back  <<<64, 256, 0, stream>>>(pbn, pbd, pbp, meta, sList, out, labels,
                                   accum, cnt0, out + BSZ * PN * 4);
}

// Round 5
// 118.456 us; speedup vs baseline: 1.0449x; 1.0449x over previous
//
#include <hip/hip_runtime.h>

#define BSZ 8
#define PN  2048
#define CIN 512
#define CAP 2048
#define NQ  4             // quarters per (b,c) list
#define KQ  512           // max elems per quarter (2048/4)

// ws layout (bytes):
//   accum @ 0       : 8 floats (S[4], imb[4])
//   cnt0  @ 32      : 1 int (k_back completion counter)
//   meta  @ 64      : 24 ints (padded list length per (b,c))
//   sList @ 1024    : 24*2048 floats (score, list order)
//   areaL @ 197632  : 24*2048 floats (area, list order)
//   roiL  @ 394240  : 24*2048 float4 (roi, list order)
//   pbn   @ 1180672 : 24*NQ*2048 floats (quarter-best numerator)
//   pbd   @ 1967104 : 24*NQ*2048 floats (quarter-best denominator)
//   pbp   @ 2753536 : 24*NQ*2048 ints   (quarter-best global list pos)
// total ~3.5 MB (L2-friendly)

// ---------------- K1: selection -> compacted per-(b,c) lists -----------------
// sel_j = (labels[b,c]!=0) && (cnt>1 ? s_j>0.5 : j==argmax(s))
// Ascending-j list order; padded to mult of 8 with copies of the last elem
// (exact ties -> resolved to lower pos downstream).
__global__ __launch_bounds__(256) void k_select(
    const float* __restrict__ ps, const float* __restrict__ labels,
    const float* __restrict__ rois, float* __restrict__ accum,
    int* __restrict__ cnt0, int* __restrict__ meta,
    float* __restrict__ sList, float* __restrict__ areaL,
    float4* __restrict__ roiList)
{
  const int bc = blockIdx.x;                        // 0..23
  const int t  = threadIdx.x;
  if (bc == 0) {
    if (t < 8) accum[t] = 0.0f;
    if (t == 8) *cnt0 = 0;
  }
  const int b = bc / 3;
  const int c = bc % 3;
  const int j0 = t * 8;

  float sv[8];
  int   flg = 0, cnt = 0;
  float vmax = -1e30f;
  int   jmax = 0;
  #pragma unroll
  for (int m = 0; m < 8; ++m) {
    const float s = ps[(b * PN + j0 + m) * 4 + c];
    sv[m] = s;
    if (s > 0.5f) { flg |= 1 << m; ++cnt; }
    if (s > vmax) { vmax = s; jmax = j0 + m; }      // ascending: > = first
  }

  __shared__ float lv[256];
  __shared__ int   lj[256];
  __shared__ int   pre[256];
  lv[t] = vmax; lj[t] = jmax; pre[t] = cnt;
  __syncthreads();
  for (int off = 128; off > 0; off >>= 1) {         // argmax reduce
    if (t < off) {
      const float v2 = lv[t + off]; const int j2 = lj[t + off];
      if (v2 > lv[t] || (v2 == lv[t] && j2 < lj[t])) { lv[t] = v2; lj[t] = j2; }
    }
    __syncthreads();
  }
  for (int off = 1; off < 256; off <<= 1) {         // inclusive scan
    const int add = (t >= off) ? pre[t - off] : 0;
    __syncthreads();
    pre[t] += add;
    __syncthreads();
  }
  const int  totalTh = pre[255];
  const int  excl    = pre[t] - cnt;
  const int  jArg    = lj[0];
  const bool lab     = labels[b * 4 + c] != 0.0f;
  const int  L    = (!lab) ? 0 : ((totalTh > 1) ? totalTh : 1);
  const int  Lpad = (L + 7) & ~7;

  __shared__ float4 lastRoi;
  __shared__ float  lastS, lastA;
  float4* dstR = roiList + bc * CAP;
  float*  dstS = sList   + bc * CAP;
  float*  dstA = areaL   + bc * CAP;
  const float4* rb = ((const float4*)rois) + b * PN;

  if (lab) {
    if (totalTh > 1) {
      int pos = excl;
      #pragma unroll
      for (int m = 0; m < 8; ++m) {
        if (flg & (1 << m)) {
          const float4 r = rb[j0 + m];
          const float  a = (r.z - r.x) * (r.w - r.y);
          dstR[pos] = r; dstS[pos] = sv[m]; dstA[pos] = a;
          if (pos == L - 1) { lastRoi = r; lastS = sv[m]; lastA = a; }
          ++pos;
        }
      }
    } else if (t == (jArg >> 3)) {
      const float4 r = rb[jArg];
      const float  a = (r.z - r.x) * (r.w - r.y);
      dstR[0] = r; dstS[0] = sv[jArg & 7]; dstA[0] = a;
      lastRoi = r; lastS = sv[jArg & 7]; lastA = a;
    }
  }
  __syncthreads();
  if (t < Lpad - L) { dstR[L + t] = lastRoi; dstS[L + t] = lastS; dstA[L + t] = lastA; }
  if (t == 0) meta[bc] = Lpad;
}

// ---------------- K2: mega = quarter-assign (0..1023) | fc+softmax (1024..) --
// Assign blocks are VALU-bound, fc blocks memory-bound -> pipes overlap.
__global__ __launch_bounds__(256) void k_mega(
    const float* __restrict__ inp, const float* __restrict__ fcw,
    const float* __restrict__ fcb, const float* __restrict__ rois,
    const int* __restrict__ meta, const float4* __restrict__ roiL,
    const float* __restrict__ areaL, float* __restrict__ logit,
    float* __restrict__ pbn, float* __restrict__ pbd, int* __restrict__ pbp)
{
  const int t    = threadIdx.x;
  const int lane = t & 63;
  const int wv   = t >> 6;

  if (blockIdx.x >= 1024) {
    // ---- fc + softmax: wave-per-4-rows, shuffle reduce ----
    const int gwv = (blockIdx.x - 1024) * 4 + wv;   // 0..4095
    const int kb  = lane << 2;
    const float4 wa0 = *(const float4*)(fcw + (kb + 0) * 4);
    const float4 wa1 = *(const float4*)(fcw + (kb + 1) * 4);
    const float4 wa2 = *(const float4*)(fcw + (kb + 2) * 4);
    const float4 wa3 = *(const float4*)(fcw + (kb + 3) * 4);
    const float4 wb0 = *(const float4*)(fcw + (256 + kb + 0) * 4);
    const float4 wb1 = *(const float4*)(fcw + (256 + kb + 1) * 4);
    const float4 wb2 = *(const float4*)(fcw + (256 + kb + 2) * 4);
    const float4 wb3 = *(const float4*)(fcw + (256 + kb + 3) * 4);
    const float4 bias = *(const float4*)fcb;
    #pragma unroll
    for (int rr = 0; rr < 4; ++rr) {
      const int r = (gwv << 2) + rr;                // row 0..16383
      const float* row = inp + r * CIN;
      const float4 xa = *(const float4*)(row + kb);
      const float4 xb = *(const float4*)(row + 256 + kb);
      float a0 = xa.x*wa0.x + xa.y*wa1.x + xa.z*wa2.x + xa.w*wa3.x
               + xb.x*wb0.x + xb.y*wb1.x + xb.z*wb2.x + xb.w*wb3.x;
      float a1 = xa.x*wa0.y + xa.y*wa1.y + xa.z*wa2.y + xa.w*wa3.y
               + xb.x*wb0.y + xb.y*wb1.y + xb.z*wb2.y + xb.w*wb3.y;
      float a2 = xa.x*wa0.z + xa.y*wa1.z + xa.z*wa2.z + xa.w*wa3.z
               + xb.x*wb0.z + xb.y*wb1.z + xb.z*wb2.z + xb.w*wb3.z;
      float a3 = xa.x*wa0.w + xa.y*wa1.w + xa.z*wa2.w + xa.w*wa3.w
               + xb.x*wb0.w + xb.y*wb1.w + xb.z*wb2.w + xb.w*wb3.w;
      #pragma unroll
      for (int off = 32; off; off >>= 1) {
        a0 += __shfl_xor(a0, off); a1 += __shfl_xor(a1, off);
        a2 += __shfl_xor(a2, off); a3 += __shfl_xor(a3, off);
      }
      if (lane == 0) {
        a0 += bias.x; a1 += bias.y; a2 += bias.z; a3 += bias.w;
        const float m  = fmaxf(fmaxf(a0, a1), fmaxf(a2, a3));
        const float e0 = expf(a0 - m), e1 = expf(a1 - m);
        const float e2 = expf(a2 - m), e3 = expf(a3 - m);
        const float inv = 1.0f / (e0 + e1 + e2 + e3);
        float4 o; o.x = e0*inv; o.y = e1*inv; o.z = e2*inv; o.w = e3*inv;
        *(float4*)(logit + r * 4) = o;
      }
    }
    return;
  }

  // ---- quarter-assign: block = (b, itile, q) ----
  const int b     = blockIdx.x >> 7;                // 8
  const int itile = (blockIdx.x >> 2) & 31;         // 32
  const int q     = blockIdx.x & 3;                 // 4

  __shared__ float4 sroi[3 * KQ];                   // 24 KB
  __shared__ float  sarea[3 * KQ];                  // 6 KB
  __shared__ float  mrgN[3][4][64];                 // 3 KB
  __shared__ float  mrgD[3][4][64];
  __shared__ int    mrgP[3][4][64];

  int qbase[3], qcnt[3];
  #pragma unroll
  for (int c = 0; c < 3; ++c) {
    const int L  = meta[b * 3 + c];                 // mult of 8
    const int K4 = (((L >> 2) + 7) & ~7);           // quarter size, mult of 8
    const int s0 = q * K4;
    int e0 = (q + 1) * K4; if (e0 > L) e0 = L;
    const int cnt = (e0 > s0) ? (e0 - s0) : 0;      // mult of 8
    qbase[c] = s0; qcnt[c] = cnt;
    for (int o = t; o < cnt; o += 256) {            // coalesced stage
      sroi [c * KQ + o] = roiL [(b * 3 + c) * CAP + s0 + o];
      sarea[c * KQ + o] = areaL[(b * 3 + c) * CAP + s0 + o];
    }
  }
  const int i = (itile << 6) + lane;
  const float4 ri = ((const float4*)rois)[b * PN + i];
  const float areai = (ri.z - ri.x) * (ri.w - ri.y);
  __syncthreads();

  auto upd = [&](float& n, float& d, int& p,
                 const float4 rj, const float aj, const int pos) {
    const float lx = fmaxf(ri.x, rj.x), ly = fmaxf(ri.y, rj.y);
    const float rx = fminf(ri.z, rj.z), ry = fminf(ri.w, rj.w);
    const float ww = fmaxf(rx - lx, 0.0f), hh = fmaxf(ry - ly, 0.0f);
    const float inter = ww * hh;
    const float uni   = areai + aj - inter;         // >= 1 always
    if (inter * d > n * uni) { n = inter; d = uni; p = pos; }
  };

  float BN[3], BD[3]; int BP[3];
  #pragma unroll
  for (int c = 0; c < 3; ++c) {
    const int cnt = qcnt[c];
    const int C   = (((cnt + 3) >> 2) + 7) & ~7;    // per-wave chunk, mult 8
    const int o0  = wv * C;
    int o1 = o0 + C; if (o1 > cnt) o1 = cnt;
    float nA = -2.0f, dA = 1.0f, nB = -2.0f, dB = 1.0f;
    int   pA = 0, pB = 0;
    const float4* rb = sroi  + c * KQ;
    const float*  ab = sarea + c * KQ;
    for (int o = o0; o < o1; o += 4) {              // dual chains, 4-prefetch
      const float4 r0 = rb[o], r1 = rb[o+1], r2 = rb[o+2], r3 = rb[o+3];
      const float  a0 = ab[o], a1 = ab[o+1], a2 = ab[o+2], a3 = ab[o+3];
      upd(nA, dA, pA, r0, a0, o);
      upd(nB, dB, pB, r2, a2, o + 2);
      upd(nA, dA, pA, r1, a1, o + 1);
      upd(nB, dB, pB, r3, a3, o + 3);
    }
    { const float xB = nB * dA, xA = nA * dB;       // tie -> lower pos
      if (xB > xA || (xB == xA && pB < pA)) { nA = nB; dA = dB; pA = pB; } }
    BN[c] = nA; BD[c] = dA; BP[c] = pA + qbase[c];  // global list pos
  }
  #pragma unroll
  for (int c = 0; c < 3; ++c) {
    mrgN[c][wv][lane] = BN[c]; mrgD[c][wv][lane] = BD[c]; mrgP[c][wv][lane] = BP[c];
  }
  __syncthreads();
  if (wv == 0) {
    #pragma unroll
    for (int c = 0; c < 3; ++c) {
      float n = BN[c], d = BD[c]; int p = BP[c];
      #pragma unroll
      for (int w = 1; w < 4; ++w) {                 // wv-ascending: > = first
        const float n2 = mrgN[c][w][lane], d2 = mrgD[c][w][lane];
        const int   p2 = mrgP[c][w][lane];
        if (n2 * d > n * d2) { n = n2; d = d2; p = p2; }
      }
      const int o = ((b * 3 + c) * NQ + q) * PN + i;
      pbn[o] = n; pbd[o] = d; pbp[o] = p;           // neutral if empty chunk
    }
  }
}

// ---------------- K3: quarter merge + epilogue + loss (fused finalize) -------
__global__ __launch_bounds__(256) void k_back(
    const float* __restrict__ pbn, const float* __restrict__ pbd,
    const int* __restrict__ pbp, const float* __restrict__ sList,
    const float* __restrict__ logit, const float* __restrict__ labels,
    float* __restrict__ accum, int* __restrict__ cnt0,
    float* __restrict__ loss)
{
  const int t  = threadIdx.x;
  const int gi = blockIdx.x * 256 + t;              // 0..16383
  const int b  = gi >> 11;
  const int i  = gi & (PN - 1);

  float v[3], sc[3];
  #pragma unroll
  for (int c = 0; c < 3; ++c) {
    const int bc = b * 3 + c;
    float n = -2.0f, d = 1.0f; int p = 0;
    #pragma unroll
    for (int qq = 0; qq < NQ; ++qq) {               // q-ascending
      const int o = (bc * NQ + qq) * PN + i;
      const float n2 = pbn[o], d2 = pbd[o];
      const int   p2 = pbp[o];
      const float x2 = n2 * d, x1 = n * d2;
      if (x2 > x1 || (x2 == x1 && p2 < p)) { n = n2; d = d2; p = p2; }
    }
    v[c]  = n / d;                                  // exact IEEE divide
    sc[c] = sList[bc * CAP + p];                    // unused unless v wins
  }
  float runI = -1.0f, runw = 1.0f;                  // empty class: v=-2 < -1
  if (v[0] > runI) { runw = sc[0]; runI = v[0]; }
  if (v[1] > runI) { runw = sc[1]; runI = v[1]; }
  if (v[2] > runI) { runw = sc[2]; runI = v[2]; }
  const float y0 = (v[0] > 0.5f) ? 1.0f : 0.0f;
  const float y1 = (v[1] > 0.5f) ? 1.0f : 0.0f;
  const float y2 = (v[2] > 0.5f) ? 1.0f : 0.0f;
  const float y3 = (y0 + y1 + y2 == 0.0f) ? 1.0f : 0.0f;

  const float4 lg = ((const float4*)logit)[gi];
  const float lb0 = labels[b * 4 + 0];
  const float lb1 = labels[b * 4 + 1];
  const float lb2 = labels[b * 4 + 2];

  auto term = [&](const float l, const float yv, const float labv) -> float {
    const float p2 = fminf(fmaxf(l, 1e-7f), 1.0f - 1e-7f);
    const float om = 1.0f - p2;
    const float fl = -yv * logf(p2) * om * om;      // focal, gamma=2
    const float wl = 10.0f * expf(l) * (1.0f - labv) + labv;
    return runw * fl * wl;                          // /imb deferred
  };
  float s[8];
  s[0] = term(lg.x, y0, lb0); s[1] = term(lg.y, y1, lb1);
  s[2] = term(lg.z, y2, lb2); s[3] = term(lg.w, y3, 1.0f);
  s[4] = y0; s[5] = y1; s[6] = y2; s[7] = y3;

  #pragma unroll
  for (int k = 0; k < 8; ++k)
    #pragma unroll
    for (int off = 32; off; off >>= 1) s[k] += __shfl_xor(s[k], off);

  __shared__ float red[4][8];
  const int wv = t >> 6;
  if ((t & 63) == 0)
    #pragma unroll
    for (int k = 0; k < 8; ++k) red[wv][k] = s[k];
  __syncthreads();
  if (t < 8) {
    const float sum = red[0][t] + red[1][t] + red[2][t] + red[3][t];
    atomicAdd(&accum[t], sum);
  }
  __syncthreads();                                  // all atomics issued
  if (t == 0) {
    __threadfence();
    if (atomicAdd(cnt0, 1) == 63) {                 // last block finalizes
      float a[8];
      #pragma unroll
      for (int k = 0; k < 8; ++k) a[k] = atomicAdd(&accum[k], 0.0f);
      float L = 0.0f;
      #pragma unroll
      for (int c = 0; c < 4; ++c) L += a[c] / (a[4 + c] + 1e-7f);
      loss[0] = L * 0.125f;                         // / bs, exact
    }
  }
}

extern "C" void kernel_launch(void* const* d_in, const int* in_sizes, int n_in,
                              void* d_out, int out_size, void* d_ws, size_t ws_size,
                              hipStream_t stream)
{
  (void)in_sizes; (void)n_in; (void)out_size; (void)ws_size;
  const float* inp    = (const float*)d_in[0];
  const float* fcw    = (const float*)d_in[1];
  const float* fcb    = (const float*)d_in[2];
  const float* ps     = (const float*)d_in[3];
  const float* labels = (const float*)d_in[4];
  const float* rois   = (const float*)d_in[5];
  float* out = (float*)d_out;                       // 65536 logit + 1 loss

  char* ws = (char*)d_ws;
  float*  accum = (float*) (ws);
  int*    cnt0  = (int*)   (ws + 32);
  int*    meta  = (int*)   (ws + 64);
  float*  sList = (float*) (ws + 1024);
  float*  areaL = (float*) (ws + 197632);
  float4* roiL  = (float4*)(ws + 394240);
  float*  pbn   = (float*) (ws + 1180672);
  float*  pbd   = (float*) (ws + 1967104);
  int*    pbp   = (int*)   (ws + 2753536);

  k_select<<<24,   256, 0, stream>>>(ps, labels, rois, accum, cnt0, meta,
                                     sList, areaL, roiL);
  k_mega  <<<2048, 256, 0, stream>>>(inp, fcw, fcb, rois, meta, roiL, areaL,
                                     out, pbn, pbd, pbp);
  k_back  <<<64,   256, 0, stream>>>(pbn, pbd, pbp, sList, out, labels,
                                     accum, cnt0, out + BSZ * PN * 4);
}